// Round 1
// baseline (694.800 us; speedup 1.0000x reference)
//
#include <hip/hip_runtime.h>

// Problem constants (fixed by reference setup_inputs)
constexpr int N_NODES = 100000;
constexpr int P_PERM  = 200000;
constexpr int L_LRP   = 16;
constexpr int D_DIM   = 64;

// workspace layout (floats)
constexpr int W2_OFF   = 0;       // [16][64][64] = weights[b][c][a] -> W2[a][b][c]
constexpr int WLT_OFF  = 65536;   // [64][64]  = w_lin[c][k] -> WLT[k][c]
constexpr int WD1T_OFF = 69632;   // [128][64] = w_deg1[c][k] -> WD1T[k][c]
constexpr int WS_FLOATS = 77824;

__global__ void zero_out_kernel(float4* __restrict__ out, int n4) {
  int i = blockIdx.x * blockDim.x + threadIdx.x;
  if (i < n4) out[i] = make_float4(0.f, 0.f, 0.f, 0.f);
}

__global__ void prep_kernel(const float* __restrict__ weights,
                            const float* __restrict__ w_lin,
                            const float* __restrict__ w_deg1,
                            float* __restrict__ ws) {
  int i = blockIdx.x * 256 + threadIdx.x;
  if (i < 65536) {
    int c = i & 63, b = (i >> 6) & 63, a = i >> 12;
    ws[W2_OFF + i] = weights[b * 1024 + c * 16 + a];
  } else if (i < 69632) {
    int j = i - 65536; int c = j & 63, k = j >> 6;
    ws[WLT_OFF + (j - 0)] = w_lin[c * 64 + k];
  } else if (i < WS_FLOATS) {
    int j = i - 69632; int c = j & 63, k = j >> 6;
    ws[WD1T_OFF + j] = w_deg1[c * 128 + k];
  }
}

// 4x4 register micro-tile GEMM step over LDS tiles Xs[p][k], Ws[k][c]
#define MICRO_GEMM(ACC, KMAX)                                          \
  _Pragma("unroll")                                                    \
  for (int kk = 0; kk < (KMAX); kk += 4) {                             \
    float xr[4][4], wr[4][4];                                          \
    _Pragma("unroll")                                                  \
    for (int i = 0; i < 4; ++i)                                        \
      *(float4*)&xr[i][0] = *(const float4*)&Xs[p0 + i][kk];           \
    _Pragma("unroll")                                                  \
    for (int u = 0; u < 4; ++u)                                        \
      *(float4*)&wr[u][0] = *(const float4*)&Ws[kk + u][c0];           \
    _Pragma("unroll")                                                  \
    for (int i = 0; i < 4; ++i)                                        \
      _Pragma("unroll")                                                \
      for (int u = 0; u < 4; ++u)                                      \
        _Pragma("unroll")                                              \
        for (int j = 0; j < 4; ++j)                                    \
          ACC[i][j] = fmaf(xr[i][u], wr[u][j], ACC[i][j]);             \
  }

__global__ __launch_bounds__(256, 4) void lrp_main_kernel(
    const float* __restrict__ nfeat,
    const float* __restrict__ degs,
    const float* __restrict__ n2p_val,
    const float* __restrict__ e2p_val,
    const float* __restrict__ pool_val,
    const float* __restrict__ bias,
    const float* __restrict__ w_deg0,
    const float* __restrict__ b_deg0,
    const float* __restrict__ b_deg1,
    const float* __restrict__ b_lin,
    const float* __restrict__ bond_emb,
    const int* __restrict__ edge_feat_idx,
    const int* __restrict__ n2p_col,
    const int* __restrict__ e2p_col,
    const int* __restrict__ pool_row,
    const float* __restrict__ ws,
    float* __restrict__ out) {
  // LDS: Xs padded to 68 so float4 rows stay 16B-aligned and bank-spread
  __shared__ float Xs[64][68];
  __shared__ float Ws[64][64];
  __shared__ float dsel[64][4];
  __shared__ float wd0[128][4];
  __shared__ float bd0[128];
  __shared__ float sbias[64];
  __shared__ float sblin[64];
  __shared__ float sbd1[64];

  const int t = threadIdx.x;
  const int pbase = blockIdx.x * 64;
  const int c0 = (t & 15) * 4;   // output-col quad
  const int p0 = (t >> 4) * 4;   // output-row quad

  // ---- stage small constants + deg_sel gather ----
  if (t < 64) { sbias[t] = bias[t]; sblin[t] = b_lin[t]; sbd1[t] = b_deg1[t]; }
  if (t >= 64 && t < 192) {
    int k = t - 64;
    bd0[k] = b_deg0[k];
    *(float4*)&wd0[k][0] = *(const float4*)&w_deg0[k * 4];
  }
  {
    int pl = t >> 2, j = t & 3;
    int r = (pbase + pl) * 16 + 5 * j;   // deg_perm.reshape(P,L)[:, ::5]
    dsel[pl][j] = n2p_val[r] * degs[n2p_col[r]];
  }
  __syncthreads();

  // ---- g = relu(deg_sel @ w_deg0^T + b_deg0) @ w_deg1^T + b_deg1 ----
  float gacc[4][4] = {};
  {
    const float* WD1T = ws + WD1T_OFF;
    for (int half = 0; half < 2; ++half) {
      // h1 half -> Xs[p][kl]
      {
        int pl = t >> 2, kq = t & 3;
        float4 dv = *(const float4*)&dsel[pl][0];
        #pragma unroll
        for (int u = 0; u < 16; ++u) {
          int kl = kq * 16 + u;
          int k = half * 64 + kl;
          float v = bd0[k];
          v = fmaf(dv.x, wd0[k][0], v);
          v = fmaf(dv.y, wd0[k][1], v);
          v = fmaf(dv.z, wd0[k][2], v);
          v = fmaf(dv.w, wd0[k][3], v);
          Xs[pl][kl] = fmaxf(v, 0.0f);
        }
      }
      // wd1T half -> Ws
      {
        const float4* src = (const float4*)(WD1T + half * 4096);
        #pragma unroll
        for (int q = 0; q < 4; ++q) {
          int idx = t + q * 256;            // 0..1023 float4s
          *(float4*)&Ws[idx >> 4][(idx & 15) * 4] = src[idx];
        }
      }
      __syncthreads();
      MICRO_GEMM(gacc, 64)
      __syncthreads();
    }
    #pragma unroll
    for (int j = 0; j < 4; ++j) {
      float bv = sbd1[c0 + j];
      #pragma unroll
      for (int i = 0; i < 4; ++i) gacc[i][j] += bv;
    }
  }

  // ---- main einsum: acc[p][c] += sum_a sum_b x[p,a,b] * W2[a][b][c] ----
  float acc[4][4] = {};
  {
    const float* W2 = ws + W2_OFF;
    for (int a = 0; a < 16; ++a) {
      // stage gathered X tile: x[p,a,b] = n2p_val*nfeat[col] + e2p_val*bond_emb[efi[ecol]]
      {
        int pl = t >> 2;
        int b0 = (t & 3) * 16;
        int r = (pbase + pl) * 16 + a;
        float nv = n2p_val[r];
        int nc = n2p_col[r];
        float ev = e2p_val[r];
        int ec = e2p_col[r];
        int be = edge_feat_idx[ec];
        const float4* nrow = (const float4*)(nfeat + nc * 64 + b0);
        const float4* erow = (const float4*)(bond_emb + be * 64 + b0);
        #pragma unroll
        for (int q = 0; q < 4; ++q) {
          float4 nf = nrow[q];
          float4 ef = erow[q];
          float4 v;
          v.x = fmaf(nv, nf.x, ev * ef.x);
          v.y = fmaf(nv, nf.y, ev * ef.y);
          v.z = fmaf(nv, nf.z, ev * ef.z);
          v.w = fmaf(nv, nf.w, ev * ef.w);
          *(float4*)&Xs[pl][b0 + q * 4] = v;
        }
      }
      // stage W2[a] slice -> Ws[b][c]
      {
        const float4* src = (const float4*)(W2 + a * 4096);
        #pragma unroll
        for (int q = 0; q < 4; ++q) {
          int idx = t + q * 256;
          *(float4*)&Ws[idx >> 4][(idx & 15) * 4] = src[idx];
        }
      }
      __syncthreads();
      MICRO_GEMM(acc, 64)
      __syncthreads();
    }
  }

  // ---- h = relu(acc + bias) @ w_lin^T + b_lin ----
  {
    #pragma unroll
    for (int i = 0; i < 4; ++i) {
      float4 v;
      v.x = fmaxf(acc[i][0] + sbias[c0 + 0], 0.f);
      v.y = fmaxf(acc[i][1] + sbias[c0 + 1], 0.f);
      v.z = fmaxf(acc[i][2] + sbias[c0 + 2], 0.f);
      v.w = fmaxf(acc[i][3] + sbias[c0 + 3], 0.f);
      *(float4*)&Xs[p0 + i][c0] = v;
    }
    const float4* src = (const float4*)(ws + WLT_OFF);
    #pragma unroll
    for (int q = 0; q < 4; ++q) {
      int idx = t + q * 256;
      *(float4*)&Ws[idx >> 4][(idx & 15) * 4] = src[idx];
    }
  }
  __syncthreads();
  float acc2[4][4] = {};
  MICRO_GEMM(acc2, 64)

  // ---- h2 = (acc2 + b_lin) * g; scatter out[pool_row[p]] += pool_val[p]*h2 ----
  #pragma unroll
  for (int i = 0; i < 4; ++i) {
    int p = pbase + p0 + i;
    int prow = pool_row[p];
    float pv = pool_val[p];
    float* orow = out + (size_t)prow * 64;
    #pragma unroll
    for (int j = 0; j < 4; ++j) {
      float h2 = (acc2[i][j] + sblin[c0 + j]) * gacc[i][j];
      atomicAdd(&orow[c0 + j], pv * h2);
    }
  }
}

extern "C" void kernel_launch(void* const* d_in, const int* in_sizes, int n_in,
                              void* d_out, int out_size, void* d_ws, size_t ws_size,
                              hipStream_t stream) {
  const float* nfeat    = (const float*)d_in[0];
  const float* degs     = (const float*)d_in[1];
  const float* n2p_val  = (const float*)d_in[2];
  const float* e2p_val  = (const float*)d_in[3];
  const float* pool_val = (const float*)d_in[4];
  const float* weights  = (const float*)d_in[5];
  const float* bias     = (const float*)d_in[6];
  const float* w_deg0   = (const float*)d_in[7];
  const float* b_deg0   = (const float*)d_in[8];
  const float* w_deg1   = (const float*)d_in[9];
  const float* b_deg1   = (const float*)d_in[10];
  const float* w_lin    = (const float*)d_in[11];
  const float* b_lin    = (const float*)d_in[12];
  const float* bond_emb = (const float*)d_in[13];
  const int* edge_feat_idx = (const int*)d_in[14];
  // d_in[15] = n2p_row (arange) unused
  const int* n2p_col    = (const int*)d_in[16];
  // d_in[17] = e2p_row (arange) unused
  const int* e2p_col    = (const int*)d_in[18];
  const int* pool_row   = (const int*)d_in[19];
  // d_in[20] = pool_col (arange) unused

  float* out = (float*)d_out;
  float* ws  = (float*)d_ws;

  int n4 = out_size / 4;  // 6.4M floats -> 1.6M float4
  zero_out_kernel<<<(n4 + 255) / 256, 256, 0, stream>>>((float4*)out, n4);
  prep_kernel<<<(WS_FLOATS + 255) / 256, 256, 0, stream>>>(weights, w_lin, w_deg1, ws);
  lrp_main_kernel<<<P_PERM / 64, 256, 0, stream>>>(
      nfeat, degs, n2p_val, e2p_val, pool_val, bias, w_deg0, b_deg0, b_deg1,
      b_lin, bond_emb, edge_feat_idx, n2p_col, e2p_col, pool_row, ws, out);
}

// Round 2
// 464.049 us; speedup vs baseline: 1.4973x; 1.4973x over previous
//
#include <hip/hip_runtime.h>
#include <hip/hip_bf16.h>

typedef __attribute__((ext_vector_type(8))) __bf16 bf16x8;
typedef __attribute__((ext_vector_type(4))) float floatx4;

constexpr int N_NODES = 100000;
constexpr int P_PERM  = 200000;

// ws layout (bytes)
constexpr size_t W2F_OFF  = 0;         // [16][2][4][64][8] bf16 = 131072 B
constexpr size_t WLF_OFF  = 131072;    // [2][4][64][8]  bf16 = 8192 B
constexpr size_t WD1F_OFF = 139264;    // [4][4][64][8]  bf16 = 16384 B
constexpr size_t NFBF_OFF = 155648;    // [100000][64]   bf16 = 12.8 MB
constexpr size_t WS_NEED_FRAGS = 155648;
constexpr size_t WS_NEED_FULL  = 155648 + (size_t)N_NODES * 64 * 2;

__global__ void zero_out_kernel(float4* __restrict__ out, int n4) {
  int i = blockIdx.x * blockDim.x + threadIdx.x;
  if (i < n4) out[i] = make_float4(0.f, 0.f, 0.f, 0.f);
}

// Pre-swizzle all B operands into MFMA B-fragment order:
// frag element j of lane l (q=l>>4,m=l&15) for (kstep ks, ctile ct) is B[k][c],
// k = ks*32 + q*8 + j, c = ct*16 + m.
__global__ void prep_w_kernel(const float* __restrict__ weights,
                              const float* __restrict__ w_lin,
                              const float* __restrict__ w_deg1,
                              __bf16* __restrict__ ws_bf) {
  int i = blockIdx.x * 256 + threadIdx.x;
  if (i < 65536) {
    int j = i & 7, l = (i >> 3) & 63, ct = (i >> 9) & 3, ks = (i >> 11) & 1, a = i >> 12;
    int k = ks * 32 + (l >> 4) * 8 + j;
    int c = ct * 16 + (l & 15);
    ws_bf[W2F_OFF / 2 + i] = (__bf16)weights[k * 1024 + c * 16 + a];
  } else if (i < 65536 + 4096) {
    int i2 = i - 65536;
    int j = i2 & 7, l = (i2 >> 3) & 63, ct = (i2 >> 9) & 3, ks = (i2 >> 11) & 1;
    int k = ks * 32 + (l >> 4) * 8 + j;
    int c = ct * 16 + (l & 15);
    ws_bf[WLF_OFF / 2 + i2] = (__bf16)w_lin[c * 64 + k];
  } else if (i < 65536 + 4096 + 8192) {
    int i3 = i - 65536 - 4096;
    int j = i3 & 7, l = (i3 >> 3) & 63, ct = (i3 >> 9) & 3, ks = (i3 >> 11) & 3;
    int k = ks * 32 + (l >> 4) * 8 + j;
    int c = ct * 16 + (l & 15);
    ws_bf[WD1F_OFF / 2 + i3] = (__bf16)w_deg1[c * 128 + k];
  }
}

__global__ void prep_feat_kernel(const float* __restrict__ nfeat,
                                 __bf16* __restrict__ nfbf) {
  int i = blockIdx.x * 256 + threadIdx.x;
  if (i >= N_NODES * 8) return;
  float4 a = *(const float4*)(nfeat + (size_t)i * 8);
  float4 b = *(const float4*)(nfeat + (size_t)i * 8 + 4);
  bf16x8 o;
  o[0] = (__bf16)a.x; o[1] = (__bf16)a.y; o[2] = (__bf16)a.z; o[3] = (__bf16)a.w;
  o[4] = (__bf16)b.x; o[5] = (__bf16)b.y; o[6] = (__bf16)b.z; o[7] = (__bf16)b.w;
  *(bf16x8*)(nfbf + (size_t)i * 8) = o;
}

template <bool BF16FEAT>
__global__ __launch_bounds__(256, 4) void lrp_mfma_kernel(
    const float* __restrict__ nfeat,
    const __bf16* __restrict__ nfbf,
    const float* __restrict__ degs,
    const float* __restrict__ n2p_val,
    const float* __restrict__ e2p_val,
    const float* __restrict__ pool_val,
    const float* __restrict__ bias,
    const float* __restrict__ w_deg0,
    const float* __restrict__ b_deg0,
    const float* __restrict__ b_deg1,
    const float* __restrict__ b_lin,
    const float* __restrict__ bond_emb,
    const int* __restrict__ edge_feat_idx,
    const int* __restrict__ n2p_col,
    const int* __restrict__ e2p_col,
    const int* __restrict__ pool_row,
    const __bf16* __restrict__ ws_bf,
    float* __restrict__ out) {
  // per-wave h-staging tile for the C-layout -> A-layout transform (no barriers!)
  __shared__ __align__(16) __bf16 hs[4][16][72];

  const int t = threadIdx.x;
  const int w = t >> 6;        // wave id in block
  const int l = t & 63;        // lane
  const int m = l & 15;        // A-row within wave tile / C-col within ctile
  const int q = l >> 4;        // quad
  const int pb = blockIdx.x * 64 + w * 16;   // wave's P base (16 rows)
  const int p  = pb + m;                      // this lane's A row

  const bf16x8* __restrict__ W2v  = (const bf16x8*)(ws_bf + W2F_OFF / 2);
  const bf16x8* __restrict__ WLv  = (const bf16x8*)(ws_bf + WLF_OFF / 2);
  const bf16x8* __restrict__ WD1v = (const bf16x8*)(ws_bf + WD1F_OFF / 2);

  // ---- main einsum: acc[ct] = sum_{a,b} x[p, a*64+b] * W2_a[b][c] ----
  floatx4 acc[4] = {{0,0,0,0},{0,0,0,0},{0,0,0,0},{0,0,0,0}};
  for (int a = 0; a < 16; ++a) {
    int r = p * 16 + a;
    float nv = n2p_val[r];
    int   nc = n2p_col[r];
    float ev = e2p_val[r];
    int   ec = e2p_col[r];
    int   be = edge_feat_idx[ec];
    #pragma unroll
    for (int ks = 0; ks < 2; ++ks) {
      int k0 = ks * 32 + q * 8;
      float xf[8];
      if (BF16FEAT) {
        bf16x8 nb = *(const bf16x8*)(nfbf + (size_t)nc * 64 + k0);
        #pragma unroll
        for (int j = 0; j < 8; ++j) xf[j] = (float)nb[j];
      } else {
        float4 n0 = *(const float4*)(nfeat + (size_t)nc * 64 + k0);
        float4 n1 = *(const float4*)(nfeat + (size_t)nc * 64 + k0 + 4);
        xf[0]=n0.x; xf[1]=n0.y; xf[2]=n0.z; xf[3]=n0.w;
        xf[4]=n1.x; xf[5]=n1.y; xf[6]=n1.z; xf[7]=n1.w;
      }
      float4 e0 = *(const float4*)(bond_emb + be * 64 + k0);
      float4 e1 = *(const float4*)(bond_emb + be * 64 + k0 + 4);
      float ef[8] = {e0.x,e0.y,e0.z,e0.w,e1.x,e1.y,e1.z,e1.w};
      bf16x8 af;
      #pragma unroll
      for (int j = 0; j < 8; ++j) af[j] = (__bf16)fmaf(nv, xf[j], ev * ef[j]);
      #pragma unroll
      for (int ct = 0; ct < 4; ++ct) {
        bf16x8 bf = W2v[((a * 2 + ks) * 4 + ct) * 64 + l];
        acc[ct] = __builtin_amdgcn_mfma_f32_16x16x32_bf16(af, bf, acc[ct], 0, 0, 0);
      }
    }
  }

  // ---- hr = relu(acc + bias) -> LDS (A-frag layout), then @ w_lin^T via MFMA ----
  {
    float biasv[4];
    #pragma unroll
    for (int ct = 0; ct < 4; ++ct) biasv[ct] = bias[ct * 16 + m];
    #pragma unroll
    for (int ct = 0; ct < 4; ++ct)
      #pragma unroll
      for (int rr = 0; rr < 4; ++rr) {
        float hv = fmaxf(acc[ct][rr] + biasv[ct], 0.0f);
        hs[w][q * 4 + rr][ct * 16 + m] = (__bf16)hv;
      }
  }
  // within-wave write->read; compiler inserts lgkmcnt wait (no barrier needed)
  floatx4 acc2[4] = {{0,0,0,0},{0,0,0,0},{0,0,0,0},{0,0,0,0}};
  #pragma unroll
  for (int ks = 0; ks < 2; ++ks) {
    bf16x8 af2 = *(const bf16x8*)&hs[w][m][ks * 32 + q * 8];
    #pragma unroll
    for (int ct = 0; ct < 4; ++ct)
      acc2[ct] = __builtin_amdgcn_mfma_f32_16x16x32_bf16(af2, WLv[(ks * 4 + ct) * 64 + l], acc2[ct], 0, 0, 0);
  }

  // ---- g-MLP: h1 = relu(deg_sel @ w_deg0^T + b_deg0); g = h1 @ w_deg1^T + b_deg1 ----
  floatx4 gacc[4] = {{0,0,0,0},{0,0,0,0},{0,0,0,0},{0,0,0,0}};
  {
    float ds0, ds1, ds2, ds3;
    {
      int r2 = p * 16;
      ds0 = n2p_val[r2 +  0] * degs[n2p_col[r2 +  0]];
      ds1 = n2p_val[r2 +  5] * degs[n2p_col[r2 +  5]];
      ds2 = n2p_val[r2 + 10] * degs[n2p_col[r2 + 10]];
      ds3 = n2p_val[r2 + 15] * degs[n2p_col[r2 + 15]];
    }
    #pragma unroll
    for (int ks = 0; ks < 4; ++ks) {
      int k0 = ks * 32 + q * 8;
      float4 bb0 = *(const float4*)(b_deg0 + k0);
      float4 bb1 = *(const float4*)(b_deg0 + k0 + 4);
      float bk[8] = {bb0.x,bb0.y,bb0.z,bb0.w,bb1.x,bb1.y,bb1.z,bb1.w};
      bf16x8 af;
      #pragma unroll
      for (int j = 0; j < 8; ++j) {
        float4 wr = *(const float4*)(w_deg0 + (k0 + j) * 4);
        float v = bk[j];
        v = fmaf(ds0, wr.x, v);
        v = fmaf(ds1, wr.y, v);
        v = fmaf(ds2, wr.z, v);
        v = fmaf(ds3, wr.w, v);
        af[j] = (__bf16)fmaxf(v, 0.0f);
      }
      #pragma unroll
      for (int ct = 0; ct < 4; ++ct)
        gacc[ct] = __builtin_amdgcn_mfma_f32_16x16x32_bf16(af, WD1v[(ks * 4 + ct) * 64 + l], gacc[ct], 0, 0, 0);
    }
  }

  // ---- h2 = (acc2 + b_lin) * (gacc + b_deg1); scatter with pool ----
  {
    float blv[4], bdv[4];
    #pragma unroll
    for (int ct = 0; ct < 4; ++ct) {
      blv[ct] = b_lin[ct * 16 + m];
      bdv[ct] = b_deg1[ct * 16 + m];
    }
    #pragma unroll
    for (int rr = 0; rr < 4; ++rr) {
      int pp = pb + q * 4 + rr;
      int prow = pool_row[pp];
      float pv = pool_val[pp];
      float* orow = out + (size_t)prow * 64;
      #pragma unroll
      for (int ct = 0; ct < 4; ++ct) {
        float h2 = (acc2[ct][rr] + blv[ct]) * (gacc[ct][rr] + bdv[ct]);
        atomicAdd(orow + ct * 16 + m, pv * h2);
      }
    }
  }
}

extern "C" void kernel_launch(void* const* d_in, const int* in_sizes, int n_in,
                              void* d_out, int out_size, void* d_ws, size_t ws_size,
                              hipStream_t stream) {
  const float* nfeat    = (const float*)d_in[0];
  const float* degs     = (const float*)d_in[1];
  const float* n2p_val  = (const float*)d_in[2];
  const float* e2p_val  = (const float*)d_in[3];
  const float* pool_val = (const float*)d_in[4];
  const float* weights  = (const float*)d_in[5];
  const float* bias     = (const float*)d_in[6];
  const float* w_deg0   = (const float*)d_in[7];
  const float* b_deg0   = (const float*)d_in[8];
  const float* w_deg1   = (const float*)d_in[9];
  const float* b_deg1   = (const float*)d_in[10];
  const float* w_lin    = (const float*)d_in[11];
  const float* b_lin    = (const float*)d_in[12];
  const float* bond_emb = (const float*)d_in[13];
  const int* edge_feat_idx = (const int*)d_in[14];
  const int* n2p_col    = (const int*)d_in[16];
  const int* e2p_col    = (const int*)d_in[18];
  const int* pool_row   = (const int*)d_in[19];

  float* out = (float*)d_out;
  __bf16* ws_bf = (__bf16*)d_ws;

  int n4 = out_size / 4;
  zero_out_kernel<<<(n4 + 255) / 256, 256, 0, stream>>>((float4*)out, n4);
  prep_w_kernel<<<(65536 + 4096 + 8192 + 255) / 256, 256, 0, stream>>>(
      weights, w_lin, w_deg1, ws_bf);

  bool use_bf16_feat = (ws_size >= WS_NEED_FULL);
  __bf16* nfbf = ws_bf + NFBF_OFF / 2;
  if (use_bf16_feat) {
    prep_feat_kernel<<<(N_NODES * 8 + 255) / 256, 256, 0, stream>>>(nfeat, nfbf);
    lrp_mfma_kernel<true><<<P_PERM / 64, 256, 0, stream>>>(
        nfeat, nfbf, degs, n2p_val, e2p_val, pool_val, bias, w_deg0, b_deg0,
        b_deg1, b_lin, bond_emb, edge_feat_idx, n2p_col, e2p_col, pool_row,
        ws_bf, out);
  } else {
    lrp_mfma_kernel<false><<<P_PERM / 64, 256, 0, stream>>>(
        nfeat, nfbf, degs, n2p_val, e2p_val, pool_val, bias, w_deg0, b_deg0,
        b_deg1, b_lin, bond_emb, edge_feat_idx, n2p_col, e2p_col, pool_row,
        ws_bf, out);
  }
}

// Round 3
// 383.012 us; speedup vs baseline: 1.8140x; 1.2116x over previous
//
#include <hip/hip_runtime.h>
#include <hip/hip_bf16.h>

typedef __attribute__((ext_vector_type(8))) __bf16 bf16x8;
typedef __attribute__((ext_vector_type(4))) float floatx4;

constexpr int N_NODES = 100000;
constexpr int P_PERM  = 200000;

// ws layout (bytes)
constexpr size_t W2F_OFF  = 0;         // [16][2][4][64][8] bf16 = 131072 B
constexpr size_t WLF_OFF  = 131072;    // [2][4][64][8]  bf16 = 8192 B
constexpr size_t WD1F_OFF = 139264;    // [4][4][64][8]  bf16 = 16384 B
constexpr size_t NFBF_OFF = 155648;    // [100000][64]   bf16 = 12.8 MB
constexpr size_t WS_NEED_FULL  = 155648 + (size_t)N_NODES * 64 * 2;

// ---- fused prep: zero d_out + weight fragment swizzle + nfeat bf16 ----
// blocks [0,6250): zero out (1.6M float4)
// blocks [6250,6554): weight frags (77824 elems)
// blocks [6554,9679): nfeat fp32 -> bf16 (800000 groups of 8)
__global__ void prep_all_kernel(float4* __restrict__ out,
                                const float* __restrict__ weights,
                                const float* __restrict__ w_lin,
                                const float* __restrict__ w_deg1,
                                const float* __restrict__ nfeat,
                                __bf16* __restrict__ ws_bf) {
  int b = blockIdx.x;
  int t = threadIdx.x;
  if (b < 6250) {
    out[b * 256 + t] = make_float4(0.f, 0.f, 0.f, 0.f);
  } else if (b < 6554) {
    int i = (b - 6250) * 256 + t;
    if (i < 65536) {
      int j = i & 7, l = (i >> 3) & 63, ct = (i >> 9) & 3, ks = (i >> 11) & 1, a = i >> 12;
      int k = ks * 32 + (l >> 4) * 8 + j;
      int c = ct * 16 + (l & 15);
      ws_bf[W2F_OFF / 2 + i] = (__bf16)weights[k * 1024 + c * 16 + a];
    } else if (i < 65536 + 4096) {
      int i2 = i - 65536;
      int j = i2 & 7, l = (i2 >> 3) & 63, ct = (i2 >> 9) & 3, ks = (i2 >> 11) & 1;
      int k = ks * 32 + (l >> 4) * 8 + j;
      int c = ct * 16 + (l & 15);
      ws_bf[WLF_OFF / 2 + i2] = (__bf16)w_lin[c * 64 + k];
    } else if (i < 65536 + 4096 + 8192) {
      int i3 = i - 65536 - 4096;
      int j = i3 & 7, l = (i3 >> 3) & 63, ct = (i3 >> 9) & 3, ks = (i3 >> 11) & 3;
      int k = ks * 32 + (l >> 4) * 8 + j;
      int c = ct * 16 + (l & 15);
      ws_bf[WD1F_OFF / 2 + i3] = (__bf16)w_deg1[c * 128 + k];
    }
  } else {
    int i = (b - 6554) * 256 + t;
    if (i < N_NODES * 8) {
      float4 a = *(const float4*)(nfeat + (size_t)i * 8);
      float4 c = *(const float4*)(nfeat + (size_t)i * 8 + 4);
      bf16x8 o;
      o[0] = (__bf16)a.x; o[1] = (__bf16)a.y; o[2] = (__bf16)a.z; o[3] = (__bf16)a.w;
      o[4] = (__bf16)c.x; o[5] = (__bf16)c.y; o[6] = (__bf16)c.z; o[7] = (__bf16)c.w;
      *(bf16x8*)(ws_bf + NFBF_OFF / 2 + (size_t)i * 8) = o;
    }
  }
}

template <bool BF16FEAT>
__global__ __launch_bounds__(256, 4) void lrp_mfma_kernel(
    const float* __restrict__ nfeat,
    const float* __restrict__ degs,
    const float* __restrict__ n2p_val,
    const float* __restrict__ e2p_val,
    const float* __restrict__ pool_val,
    const float* __restrict__ bias,
    const float* __restrict__ w_deg0,
    const float* __restrict__ b_deg0,
    const float* __restrict__ b_deg1,
    const float* __restrict__ b_lin,
    const float* __restrict__ bond_emb,
    const int* __restrict__ edge_feat_idx,
    const int* __restrict__ n2p_col,
    const int* __restrict__ e2p_col,
    const int* __restrict__ pool_row,
    const __bf16* __restrict__ ws_bf,
    float* __restrict__ out) {
  // hs: per-wave, per-ptile C->A layout staging. rows padded to 72 (144 B = 9*16B)
  __shared__ __align__(16) __bf16 hs[4][2][16][72];
  __shared__ __align__(16) __bf16 sbond[4][72];   // bond_emb bf16, padded rows

  const int t = threadIdx.x;
  const int w = t >> 6;
  const int l = t & 63;
  const int m = l & 15;
  const int q = l >> 4;
  const int pbw = blockIdx.x * 128 + w * 32;   // wave covers 32 p rows
  int pc[2];
  pc[0] = min(pbw + m, P_PERM - 1);
  pc[1] = min(pbw + 16 + m, P_PERM - 1);

  // stage bond_emb (4x64 fp32 -> bf16) into LDS
  if (t < 256) sbond[t >> 6][t & 63] = (__bf16)bond_emb[t];
  __syncthreads();

  const __bf16* __restrict__ nfbf = ws_bf + NFBF_OFF / 2;
  const bf16x8* __restrict__ W2v  = (const bf16x8*)(ws_bf + W2F_OFF / 2);
  const bf16x8* __restrict__ WLv  = (const bf16x8*)(ws_bf + WLF_OFF / 2);
  const bf16x8* __restrict__ WD1v = (const bf16x8*)(ws_bf + WD1F_OFF / 2);

  // ---- main einsum ----
  floatx4 acc[2][4] = {};
  #pragma unroll 1
  for (int rr8 = 0; rr8 < 8; ++rr8) {
    const int aa = rr8 * 2;
    float2 nv2[2], ev2[2];
    int2 nc2[2], ec2[2];
    #pragma unroll
    for (int pt = 0; pt < 2; ++pt) {
      size_t rb = (size_t)pc[pt] * 16 + aa;
      nv2[pt] = *(const float2*)(n2p_val + rb);
      nc2[pt] = *(const int2*)(n2p_col + rb);
      ev2[pt] = *(const float2*)(e2p_val + rb);
      ec2[pt] = *(const int2*)(e2p_col + rb);
    }
    int be[2][2];
    #pragma unroll
    for (int pt = 0; pt < 2; ++pt) {
      be[pt][0] = edge_feat_idx[ec2[pt].x];
      be[pt][1] = edge_feat_idx[ec2[pt].y];
    }
    // issue all feature gathers for this round
    bf16x8 nb[2][2][2];     // [pt][u][ks]
    float4 nf32[2][2][2][2]; // fallback path
    #pragma unroll
    for (int pt = 0; pt < 2; ++pt)
      #pragma unroll
      for (int u = 0; u < 2; ++u) {
        int nc = u ? nc2[pt].y : nc2[pt].x;
        #pragma unroll
        for (int ks = 0; ks < 2; ++ks) {
          int k0 = ks * 32 + q * 8;
          if (BF16FEAT) {
            nb[pt][u][ks] = *(const bf16x8*)(nfbf + (size_t)nc * 64 + k0);
          } else {
            nf32[pt][u][ks][0] = *(const float4*)(nfeat + (size_t)nc * 64 + k0);
            nf32[pt][u][ks][1] = *(const float4*)(nfeat + (size_t)nc * 64 + k0 + 4);
          }
        }
      }
    bf16x8 eb[2][2][2];
    #pragma unroll
    for (int pt = 0; pt < 2; ++pt)
      #pragma unroll
      for (int u = 0; u < 2; ++u)
        #pragma unroll
        for (int ks = 0; ks < 2; ++ks)
          eb[pt][u][ks] = *(const bf16x8*)&sbond[be[pt][u]][ks * 32 + q * 8];

    // compute
    #pragma unroll
    for (int u = 0; u < 2; ++u) {
      const int a = aa + u;
      #pragma unroll
      for (int ks = 0; ks < 2; ++ks) {
        bf16x8 af[2];
        #pragma unroll
        for (int pt = 0; pt < 2; ++pt) {
          float nv = u ? nv2[pt].y : nv2[pt].x;
          float ev = u ? ev2[pt].y : ev2[pt].x;
          #pragma unroll
          for (int j = 0; j < 8; ++j) {
            float xf = BF16FEAT ? (float)nb[pt][u][ks][j]
                                : ((const float*)&nf32[pt][u][ks][0])[j];
            float ef = (float)eb[pt][u][ks][j];
            af[pt][j] = (__bf16)fmaf(nv, xf, ev * ef);
          }
        }
        #pragma unroll
        for (int ct = 0; ct < 4; ++ct) {
          bf16x8 bf = W2v[((a * 2 + ks) * 4 + ct) * 64 + l];
          acc[0][ct] = __builtin_amdgcn_mfma_f32_16x16x32_bf16(af[0], bf, acc[0][ct], 0, 0, 0);
          acc[1][ct] = __builtin_amdgcn_mfma_f32_16x16x32_bf16(af[1], bf, acc[1][ct], 0, 0, 0);
        }
      }
    }
  }

  // ---- hr = relu(acc + bias) -> LDS (A-frag layout) -> @ w_lin^T ----
  floatx4 acc2[2][4] = {};
  {
    float biasv[4];
    #pragma unroll
    for (int ct = 0; ct < 4; ++ct) biasv[ct] = bias[ct * 16 + m];
    #pragma unroll
    for (int pt = 0; pt < 2; ++pt)
      #pragma unroll
      for (int ct = 0; ct < 4; ++ct)
        #pragma unroll
        for (int rr = 0; rr < 4; ++rr)
          hs[w][pt][q * 4 + rr][ct * 16 + m] =
              (__bf16)fmaxf(acc[pt][ct][rr] + biasv[ct], 0.0f);
    #pragma unroll
    for (int pt = 0; pt < 2; ++pt)
      #pragma unroll
      for (int ks = 0; ks < 2; ++ks) {
        bf16x8 af2 = *(const bf16x8*)&hs[w][pt][m][ks * 32 + q * 8];
        #pragma unroll
        for (int ct = 0; ct < 4; ++ct)
          acc2[pt][ct] = __builtin_amdgcn_mfma_f32_16x16x32_bf16(
              af2, WLv[(ks * 4 + ct) * 64 + l], acc2[pt][ct], 0, 0, 0);
      }
  }

  // ---- g-MLP ----
  floatx4 gacc[2][4] = {};
  {
    float ds[2][4];
    #pragma unroll
    for (int pt = 0; pt < 2; ++pt) {
      size_t rp = (size_t)pc[pt] * 16;
      #pragma unroll
      for (int jj = 0; jj < 4; ++jj)
        ds[pt][jj] = n2p_val[rp + 5 * jj] * degs[n2p_col[rp + 5 * jj]];
    }
    #pragma unroll
    for (int ks = 0; ks < 4; ++ks) {
      int k0 = ks * 32 + q * 8;
      float4 bb0 = *(const float4*)(b_deg0 + k0);
      float4 bb1 = *(const float4*)(b_deg0 + k0 + 4);
      float bk[8] = {bb0.x, bb0.y, bb0.z, bb0.w, bb1.x, bb1.y, bb1.z, bb1.w};
      bf16x8 af[2];
      #pragma unroll
      for (int j = 0; j < 8; ++j) {
        float4 wr = *(const float4*)(w_deg0 + (k0 + j) * 4);
        #pragma unroll
        for (int pt = 0; pt < 2; ++pt) {
          float v = bk[j];
          v = fmaf(ds[pt][0], wr.x, v);
          v = fmaf(ds[pt][1], wr.y, v);
          v = fmaf(ds[pt][2], wr.z, v);
          v = fmaf(ds[pt][3], wr.w, v);
          af[pt][j] = (__bf16)fmaxf(v, 0.0f);
        }
      }
      #pragma unroll
      for (int ct = 0; ct < 4; ++ct) {
        bf16x8 bf = WD1v[(ks * 4 + ct) * 64 + l];
        gacc[0][ct] = __builtin_amdgcn_mfma_f32_16x16x32_bf16(af[0], bf, gacc[0][ct], 0, 0, 0);
        gacc[1][ct] = __builtin_amdgcn_mfma_f32_16x16x32_bf16(af[1], bf, gacc[1][ct], 0, 0, 0);
      }
    }
  }

  // ---- h2 = (acc2 + b_lin) * (gacc + b_deg1); pooled scatter ----
  {
    float blv[4], bdv[4];
    #pragma unroll
    for (int ct = 0; ct < 4; ++ct) {
      blv[ct] = b_lin[ct * 16 + m];
      bdv[ct] = b_deg1[ct * 16 + m];
    }
    #pragma unroll
    for (int pt = 0; pt < 2; ++pt)
      #pragma unroll
      for (int rr = 0; rr < 4; ++rr) {
        int pp = pbw + pt * 16 + q * 4 + rr;
        if (pp < P_PERM) {
          int prow = pool_row[pp];
          float pv = pool_val[pp];
          float* orow = out + (size_t)prow * 64;
          #pragma unroll
          for (int ct = 0; ct < 4; ++ct) {
            float h2 = (acc2[pt][ct][rr] + blv[ct]) * (gacc[pt][ct][rr] + bdv[ct]);
            atomicAdd(orow + ct * 16 + m, pv * h2);
          }
        }
      }
  }
}

extern "C" void kernel_launch(void* const* d_in, const int* in_sizes, int n_in,
                              void* d_out, int out_size, void* d_ws, size_t ws_size,
                              hipStream_t stream) {
  const float* nfeat    = (const float*)d_in[0];
  const float* degs     = (const float*)d_in[1];
  const float* n2p_val  = (const float*)d_in[2];
  const float* e2p_val  = (const float*)d_in[3];
  const float* pool_val = (const float*)d_in[4];
  const float* weights  = (const float*)d_in[5];
  const float* bias     = (const float*)d_in[6];
  const float* w_deg0   = (const float*)d_in[7];
  const float* b_deg0   = (const float*)d_in[8];
  const float* w_deg1   = (const float*)d_in[9];
  const float* b_deg1   = (const float*)d_in[10];
  const float* w_lin    = (const float*)d_in[11];
  const float* b_lin    = (const float*)d_in[12];
  const float* bond_emb = (const float*)d_in[13];
  const int* edge_feat_idx = (const int*)d_in[14];
  const int* n2p_col    = (const int*)d_in[16];
  const int* e2p_col    = (const int*)d_in[18];
  const int* pool_row   = (const int*)d_in[19];

  float* out = (float*)d_out;
  __bf16* ws_bf = (__bf16*)d_ws;

  prep_all_kernel<<<9679, 256, 0, stream>>>((float4*)out, weights, w_lin,
                                            w_deg1, nfeat, ws_bf);

  int grid = (P_PERM + 127) / 128;  // 1563
  if (ws_size >= WS_NEED_FULL) {
    lrp_mfma_kernel<true><<<grid, 256, 0, stream>>>(
        nfeat, degs, n2p_val, e2p_val, pool_val, bias, w_deg0, b_deg0,
        b_deg1, b_lin, bond_emb, edge_feat_idx, n2p_col, e2p_col, pool_row,
        ws_bf, out);
  } else {
    lrp_mfma_kernel<false><<<grid, 256, 0, stream>>>(
        nfeat, degs, n2p_val, e2p_val, pool_val, bias, w_deg0, b_deg0,
        b_deg1, b_lin, bond_emb, edge_feat_idx, n2p_col, e2p_col, pool_row,
        ws_bf, out);
  }
}